// Round 6
// baseline (107.625 us; speedup 1.0000x reference)
//
#include <hip/hip_runtime.h>
#include <math.h>

#define DET 512
#define NA  180
#define OUT 362   // floor(sqrt(512^2/2))
#define RAD 181   // OUT/2
#define OUTSQ (OUT * OUT)
#define NB  4     // batch size (fixed by the problem: x is (4,1,512,180))

#define NSPLIT 12       // angle partitions per tile (all 4 b's fused per block)
#define APB    15       // angles per block (NA / NSPLIT)
#define CHUNK  5        // angle lines staged per barrier
#define LQ     514      // float4 quads per staged line (512 data + 2 zero quads)

// ---------------------------------------------------------------------------
// Compile-time tables / weights.
// ---------------------------------------------------------------------------
constexpr double PI_D = 3.14159265358979323846;

constexpr double tsin(double x) {  // |x| <= pi/4
    double x2 = x * x;
    return x * (1.0 + x2 * (-1.0/6 + x2 * (1.0/120 + x2 * (-1.0/5040 +
               x2 * (1.0/362880 + x2 * (-1.0/39916800))))));
}
constexpr double tcos(double x) {  // |x| <= pi/4
    double x2 = x * x;
    return 1.0 + x2 * (-0.5 + x2 * (1.0/24 + x2 * (-1.0/720 +
               x2 * (1.0/40320 + x2 * (-1.0/3628800)))));
}

struct Trig { float c[NA]; float s[NA]; };
constexpr Trig make_trig() {
    Trig t{};
    constexpr double r = PI_D / 180.0;
    for (int k = 0; k < NA; ++k) {
        double c, s;
        if (k <= 45)       { c =  tcos(k * r);          s =  tsin(k * r); }
        else if (k <= 90)  { c =  tsin((90 - k) * r);   s =  tcos((90 - k) * r); }
        else if (k <= 135) { c = -tsin((k - 90) * r);   s =  tcos((k - 90) * r); }
        else               { c = -tcos((180 - k) * r);  s =  tsin((180 - k) * r); }
        t.c[k] = (float)c; t.s[k] = (float)s;
    }
    return t;
}
__device__ constexpr Trig TRIG = make_trig();

// Ramp weight for odd offset m: w(m) = -2/(pi*m)^2; 0 outside [-511,511] or
// for even m.  ONLY used in constexpr context (template args / if constexpr)
// so it folds to a 32-bit float literal (R4 lesson: runtime eval = 90 us).
__host__ __device__ constexpr float rampw0(int m) {
    int a = m < 0 ? -m : m;
    if (a > 511 || (a & 1) == 0) return 0.0f;
    double md = (double)a;
    return (float)(-2.0 / (PI_D * PI_D * md * md));
}

// One tap: v = p[R] feeds the 4 accumulators with compile-time weights.
template<int R>
__device__ __forceinline__ void tap(const float* __restrict__ p,
        float& a0, float& a1, float& a2, float& a3) {
    const float v = p[R];
    if constexpr (rampw0(R)      != 0.0f) a0 = fmaf(rampw0(R),      v, a0);
    if constexpr (rampw0(R - 32) != 0.0f) a1 = fmaf(rampw0(R - 32), v, a1);
    if constexpr (rampw0(R - 64) != 0.0f) a2 = fmaf(rampw0(R - 64), v, a2);
    if constexpr (rampw0(R - 96) != 0.0f) a3 = fmaf(rampw0(R - 96), v, a3);
}

// Straight-line sweep over odd offsets R, R+2, ..., REND (template recursion:
// guaranteed full unroll, literal weights).
template<int R, int REND>
__device__ __forceinline__ void sweep(const float* __restrict__ p,
        float& a0, float& a1, float& a2, float& a3) {
    if constexpr (R <= REND) {
        tap<R>(p, a0, a1, a2, a3);
        sweep<R + 2, REND>(p, a0, a1, a2, a3);
    }
}

// ---------------------------------------------------------------------------
// Kernel 1: ramp filter, literal-weight tap-sharing form, 4 window-quarters.
// Block = 512 threads = 1 (b, angle) line; t = tid&127 owns outputs
// q, q+32, q+64, q+96 with q = (t&31) + 128*(t>>5); qtr = tid>>7 sweeps one
// 140-tap quarter of the odd-offset window [-511, 607]; quarters combined
// via an LDS reduction.  8 waves/block -> ~22 waves/CU for latency hiding
// (R5's 2-half version ran at 2.8 waves/SIMD and was latency-limited ~16us).
// Output layout: ft[a][d][b] (batch-interleaved float4 per detector bin) so
// the backprojector can serve all 4 images from one ds_read_b128 pair.
// ---------------------------------------------------------------------------
__global__ __launch_bounds__(512) void ramp_filter_kernel(
        const float* __restrict__ x, float* __restrict__ ft) {
    const int a   = blockIdx.x;
    const int b   = blockIdx.y;
    const int tid = threadIdx.x;        // 0..511
    const int t   = tid & 127;          // output-thread id
    const int qtr = tid >> 7;           // window quarter 0..3
    const int q = (t & 31) + 128 * (t >> 5);   // base output (covers all 512)

    __shared__ float xs[3 * DET];       // [0,512) zeros | data | [1024,1536) zeros
    __shared__ float red[3][4][128];    // quarter 1..3 partial accumulators

    // stage + zero pads (x is (B,1,DET,NA): strided column read, L2-served)
    xs[tid]        = 0.0f;
    xs[1024 + tid] = 0.0f;
    xs[512 + tid]  = x[(b * DET + tid) * NA + a];
    __syncthreads();

    const float* p = xs + 512 + q;
    float a0 = 0.0f, a1 = 0.0f, a2 = 0.0f, a3 = 0.0f;

    if (qtr == 0) {
        a0 = 0.5f * p[0];               // center taps (weight 0.5), once
        a1 = 0.5f * p[32];
        a2 = 0.5f * p[64];
        a3 = 0.5f * p[96];
        sweep<-511, -233>(p, a0, a1, a2, a3);
    } else if (qtr == 1) {
        sweep<-231, 47>(p, a0, a1, a2, a3);
    } else if (qtr == 2) {
        sweep<49, 327>(p, a0, a1, a2, a3);
    } else {
        sweep<329, 607>(p, a0, a1, a2, a3);
    }
    if (qtr != 0) {
        red[qtr - 1][0][t] = a0;
        red[qtr - 1][1][t] = a1;
        red[qtr - 1][2][t] = a2;
        red[qtr - 1][3][t] = a3;
    }
    __syncthreads();

    if (qtr == 0) {
        // batch-interleaved store: ft[(a*DET + d)*4 + b]
        float* ob = ft + ((size_t)a * DET + q) * NB + b;
        ob[0 * 4 * NB / 4 * 0] = 0.0f;  // (dummy no-op removed by compiler)
        ob[0]        = a0 + red[0][0][t] + red[1][0][t] + red[2][0][t];
        ob[32 * NB]  = a1 + red[0][1][t] + red[1][1][t] + red[2][1][t];
        ob[64 * NB]  = a2 + red[0][2][t] + red[1][2][t] + red[2][2][t];
        ob[96 * NB]  = a3 + red[0][3][t] + red[1][3][t] + red[2][3][t];
    }
}

// ---------------------------------------------------------------------------
// Kernel 2: backprojection, batch-of-4 fused.  Grid (12,12,NSPLIT); 32x32
// pixel tile; 4 pixels/thread x 4 images.  Staged lines are float4-per-bin
// (b0..b3), so ONE pair of ds_read_b128 serves 4 interps and all index math
// (floor/fract/addr/guard) is batch-invariant -> ~4x less VALU, ~2x less LDS
// pipe than the per-b version (R5: 40.7us, VALU 25.6us, LDS ~31us).
// Zero quads at [512],[513] catch the pos>511 guard redirect; pos==511.0
// exact lerps against the [512] zero quad (matches reference in_range).
// ---------------------------------------------------------------------------
__device__ __forceinline__ void acc4(float4& acc,
        const float4* __restrict__ L, float pos) {
    float pf = floorf(pos);
    float fr = pos - pf;
    int   i0 = (int)pf;                       // pos in [0.03, 511.97] -> 0..511
    const float4* q = (pos > (float)(DET - 1)) ? (L + DET) : (L + i0);
    float4 g0 = q[0];
    float4 g1 = q[1];
    acc.x += fmaf(fr, g1.x - g0.x, g0.x);
    acc.y += fmaf(fr, g1.y - g0.y, g0.y);
    acc.z += fmaf(fr, g1.z - g0.z, g0.z);
    acc.w += fmaf(fr, g1.w - g0.w, g0.w);
}

__global__ __launch_bounds__(256) void backproject_kernel(
        const float4* __restrict__ ftq, float* __restrict__ out) {
    const int sp = blockIdx.z;               // angle partition (b's fused)
    const int r0 = blockIdx.y * 32;
    const int c0 = blockIdx.x * 32;
    const int tid = threadIdx.x;
    const int tx = tid & 15;
    const int ty = tid >> 4;

    __shared__ float4 lines[CHUNK][LQ];

    // zero sentinel quads at [c][512], [c][513] (never overwritten by staging)
    if (tid < 2 * CHUNK)
        lines[tid >> 1][DET + (tid & 1)] = float4{0.0f, 0.0f, 0.0f, 0.0f};

    // clamp base coordinate for guard pixels (r/c >= OUT) so their pos stays
    // in-range; their stores are guarded off below.
    const float xpr = (float)(min(r0 + ty, OUT - 1) - RAD);   // row coord
    const float ypr = (float)(min(c0 + tx, OUT - 1) - RAD);   // col coord

    float4 a00 = {0,0,0,0}, a01 = {0,0,0,0}, a10 = {0,0,0,0}, a11 = {0,0,0,0};

    for (int rd = 0; rd < APB / CHUNK; ++rd) {
        __syncthreads();
        const float4* g = ftq + (size_t)(sp * APB + rd * CHUNK) * DET;
        #pragma unroll
        for (int k = 0; k < CHUNK * DET / 256; ++k) {   // 10
            int j = tid + k * 256;                      // quad index in chunk
            lines[j >> 9][j & 511] = g[j];
        }
        __syncthreads();

        const int abase = sp * APB + rd * CHUNK;
        #pragma unroll
        for (int i = 0; i < CHUNK; ++i) {
            const float cv = TRIG.c[abase + i];
            const float sv = TRIG.s[abase + i];
            // pos = ypr*cos - xpr*sin + det/2
            float p00 = fmaf(ypr, cv, fmaf(xpr, -sv, 256.0f));
            float p01 = fmaf(16.0f, cv, p00);       // col+16
            float p10 = fmaf(-16.0f, sv, p00);      // row+16
            float p11 = fmaf(-16.0f, sv, p01);      // row+16, col+16
            const float4* L = &lines[i][0];
            acc4(a00, L, p00);
            acc4(a01, L, p01);
            acc4(a10, L, p10);
            acc4(a11, L, p11);
        }
    }

    const float scale = (float)(PI_D / (2.0 * NA));
    const int r = r0 + ty;
    const int c = c0 + tx;

#define EMIT(ACC, RR, CC)                                          \
    if ((RR) < OUT && (CC) < OUT) {                                \
        const int off = (RR) * OUT + (CC);                         \
        atomicAdd(out + off,             (ACC).x * scale);         \
        atomicAdd(out + OUTSQ + off,     (ACC).y * scale);         \
        atomicAdd(out + 2 * OUTSQ + off, (ACC).z * scale);         \
        atomicAdd(out + 3 * OUTSQ + off, (ACC).w * scale);         \
    }
    EMIT(a00, r, c);
    EMIT(a01, r, c + 16);
    EMIT(a10, r + 16, c);
    EMIT(a11, r + 16, c + 16);
#undef EMIT
}

extern "C" void kernel_launch(void* const* d_in, const int* in_sizes, int n_in,
                              void* d_out, int out_size, void* d_ws, size_t ws_size,
                              hipStream_t stream) {
    const float* x = (const float*)d_in[0];
    float* ft  = (float*)d_ws;     // NA*DET*NB*4 = 1.47 MB scratch, b-interleaved
    float* out = (float*)d_out;

    const int B = in_sizes[0] / (DET * NA);   // 4 (problem is fixed at B=4)

    hipMemsetAsync(out, 0, (size_t)out_size * sizeof(float), stream);
    ramp_filter_kernel<<<dim3(NA, B), 512, 0, stream>>>(x, ft);
    backproject_kernel<<<dim3((OUT + 31) / 32, (OUT + 31) / 32, NSPLIT),
                         256, 0, stream>>>((const float4*)ft, out);
}